// Round 1
// 978.132 us; speedup vs baseline: 1.0970x; 1.0970x over previous
//
#include <hip/hip_runtime.h>
#include <math.h>

#define TTOK 2048
#define NEXP 16
#define HDIM 2048
#define IDIM 1408
#define TOPK 4

typedef __attribute__((ext_vector_type(8))) short short8;
typedef __attribute__((ext_vector_type(4))) float floatx4;

#define GUP ((size_t)NEXP * IDIM * HDIM)  // elems in gate_w / up_w / down_w (46.1M each)

#define LDSP(p) ((__attribute__((address_space(3))) void*)(p))
#define GLBP(p) ((const __attribute__((address_space(1))) void*)(p))

__device__ __forceinline__ unsigned short f2bf(float f) {
    unsigned u = __builtin_bit_cast(unsigned, f);
    u += 0x7FFFu + ((u >> 16) & 1u);   // round-to-nearest-even
    return (unsigned short)(u >> 16);
}

__device__ __forceinline__ void cvt8(const float* __restrict__ s, unsigned short* __restrict__ d) {
    const float4* sv = (const float4*)s;
    float4 a = sv[0], b = sv[1];
    union { unsigned short h[8]; uint4 v; } p;
    p.h[0] = f2bf(a.x); p.h[1] = f2bf(a.y); p.h[2] = f2bf(a.z); p.h[3] = f2bf(a.w);
    p.h[4] = f2bf(b.x); p.h[5] = f2bf(b.y); p.h[6] = f2bf(b.z); p.h[7] = f2bf(b.w);
    *(uint4*)d = p.v;
}

__global__ void zero_i32(int* __restrict__ p, int n) {
    int i = threadIdx.x;
    if (i < n) p[i] = 0;
}

// fp32 -> bf16 cast of the three weight tensors (8 elems/thread/array per iter)
__global__ void cast_weights(const float* __restrict__ g, const float* __restrict__ u,
                             const float* __restrict__ d,
                             unsigned short* __restrict__ og, unsigned short* __restrict__ ou,
                             unsigned short* __restrict__ od) {
    size_t i = ((size_t)blockIdx.x * blockDim.x + threadIdx.x) * 8;
    size_t stride = (size_t)gridDim.x * blockDim.x * 8;
    for (; i < GUP; i += stride) {
        cvt8(g + i, og + i);
        cvt8(u + i, ou + i);
        cvt8(d + i, od + i);
    }
}

// One thread per token: top-4 of 16 logits, softmax over the top-4, scatter
// (token, weight) into per-expert lists; also record (expert,slot) per token
// for the final gather-reduce.
__global__ void router_kernel(const float* __restrict__ logits,
                              int* __restrict__ cnt,
                              int* __restrict__ tok_id,
                              float* __restrict__ tok_w,
                              int* __restrict__ tk_ep) {
    int t = blockIdx.x * blockDim.x + threadIdx.x;
    if (t >= TTOK) return;
    float l[NEXP];
#pragma unroll
    for (int e = 0; e < NEXP; ++e) l[e] = logits[t * NEXP + e];
    int bi[TOPK]; float bv[TOPK];
    unsigned used = 0;
#pragma unroll
    for (int k = 0; k < TOPK; ++k) {
        float best = -1e30f; int b = 0;
#pragma unroll
        for (int e = 0; e < NEXP; ++e) {
            if (!((used >> e) & 1u) && l[e] > best) { best = l[e]; b = e; }
        }
        used |= 1u << b; bi[k] = b; bv[k] = best;
    }
    float m = bv[0], w[TOPK], s = 0.f;
#pragma unroll
    for (int k = 0; k < TOPK; ++k) { w[k] = expf(bv[k] - m); s += w[k]; }
    float inv = 1.f / s;
#pragma unroll
    for (int k = 0; k < TOPK; ++k) {
        int e = bi[k];
        int pos = atomicAdd(&cnt[e], 1);
        tok_id[e * TTOK + pos] = t;
        tok_w[e * TTOK + pos] = w[k] * inv;
        tk_ep[t * TOPK + k] = (e << 16) | pos;
    }
}

// Cumulative offsets with each expert padded to a multiple of 128 rows.
__global__ void scan_kernel(const int* __restrict__ cnt, int* __restrict__ offs) {
    if (threadIdx.x == 0 && blockIdx.x == 0) {
        int a = 0;
        for (int e = 0; e < NEXP; ++e) {
            offs[e] = a;
            a += (cnt[e] + 127) & ~127;
        }
        offs[NEXP] = a;
    }
}

// Gather + cast x rows into compact padded per-expert layout (pad rows zeroed).
__global__ void gather_x(const float* __restrict__ x, const int* __restrict__ cnt,
                         const int* __restrict__ offs, const int* __restrict__ tok_id,
                         unsigned short* __restrict__ xg) {
    int e = blockIdx.y, slot = blockIdx.x;
    int n = cnt[e];
    int padcap = (n + 127) & ~127;
    if (slot >= padcap) return;
    unsigned short* dst = xg + (size_t)(offs[e] + slot) * HDIM;
    int tid = threadIdx.x;  // 256 threads, 8 elems each = 2048
    if (slot < n) {
        const float* src = x + (size_t)tok_id[e * TTOK + slot] * HDIM;
        cvt8(src + tid * 8, dst + tid * 8);
    } else {
        uint4 z = {0u, 0u, 0u, 0u};
        ((uint4*)dst)[tid] = z;
    }
}

// Fused gate+up MFMA GEMM: 128x128 tile, BK=32, double-buffered LDS with a
// single barrier per K-step (stage next slab, then compute current one).
// BK=32 -> 64B LDS row stride makes the b128 fragment reads bank-balanced.
__launch_bounds__(256)
__global__ void gateup_mfma(const unsigned short* __restrict__ xg,
                            const unsigned short* __restrict__ gw,
                            const unsigned short* __restrict__ uw,
                            const int* __restrict__ cnt, const int* __restrict__ offs,
                            const float* __restrict__ tok_w,
                            unsigned short* __restrict__ hbuf) {
    const int e = blockIdx.z;
    const int n = cnt[e];
    const int m0 = blockIdx.y * 128;
    if (m0 >= n) return;
    const int i0 = blockIdx.x * 128;
    const int rowbase = offs[e];

    __shared__ __align__(16) unsigned short sA[2][128 * 32];
    __shared__ __align__(16) unsigned short sBg[2][128 * 32];
    __shared__ __align__(16) unsigned short sBu[2][128 * 32];

    const int tid = threadIdx.x;
    const int lane = tid & 63;
    const int wave = tid >> 6;
    const int wm = wave >> 1;
    const int wn = wave & 1;

    const unsigned short* Abase = xg + (size_t)(rowbase + m0) * HDIM;
    const unsigned short* Gbase = gw + (size_t)e * IDIM * HDIM + (size_t)i0 * HDIM;
    const unsigned short* Ubase = uw + (size_t)e * IDIM * HDIM + (size_t)i0 * HDIM;

    floatx4 accg[4][4], accu[4][4];
#pragma unroll
    for (int i = 0; i < 4; ++i)
#pragma unroll
        for (int j = 0; j < 4; ++j) {
            accg[i][j] = (floatx4){0.f, 0.f, 0.f, 0.f};
            accu[i][j] = (floatx4){0.f, 0.f, 0.f, 0.f};
        }

    const int srow = lane >> 2;        // row within a 16-row chunk
    const int scol = (lane & 3) * 8;   // elem col within the 32-wide K slab

    auto stage = [&](int buf, int k0) {
#pragma unroll
        for (int q = 0; q < 2; ++q) {
            const int ch = q * 4 + wave;            // 8 chunks of 16 rows
            const int r = ch * 16 + srow;
            const size_t go = (size_t)r * HDIM + k0 + scol;
            const int lo = ch * 512 + lane * 8;     // linear row-major [128][32]
            __builtin_amdgcn_global_load_lds(GLBP(Abase + go), LDSP(&sA[buf][lo]), 16, 0, 0);
            __builtin_amdgcn_global_load_lds(GLBP(Gbase + go), LDSP(&sBg[buf][lo]), 16, 0, 0);
            __builtin_amdgcn_global_load_lds(GLBP(Ubase + go), LDSP(&sBu[buf][lo]), 16, 0, 0);
        }
    };

    stage(0, 0);
    __syncthreads();

    const int ko = (lane >> 4) * 8;
    const int mrow = wm * 64 + (lane & 15);
    const int nrow = wn * 64 + (lane & 15);

    int cur = 0;
    for (int k0 = 0; k0 < HDIM; k0 += 32) {
        const int nb = cur ^ 1;
        if (k0 + 32 < HDIM) stage(nb, k0 + 32);   // prefetch next slab (async)

        short8 af[4], bg[4], bu[4];
#pragma unroll
        for (int i = 0; i < 4; ++i)
            af[i] = *(const short8*)&sA[cur][(mrow + i * 16) * 32 + ko];
#pragma unroll
        for (int j = 0; j < 4; ++j) {
            bg[j] = *(const short8*)&sBg[cur][(nrow + j * 16) * 32 + ko];
            bu[j] = *(const short8*)&sBu[cur][(nrow + j * 16) * 32 + ko];
        }
#pragma unroll
        for (int i = 0; i < 4; ++i)
#pragma unroll
            for (int j = 0; j < 4; ++j) {
                accg[i][j] = __builtin_amdgcn_mfma_f32_16x16x32_bf16(af[i], bg[j], accg[i][j], 0, 0, 0);
                accu[i][j] = __builtin_amdgcn_mfma_f32_16x16x32_bf16(af[i], bu[j], accu[i][j], 0, 0, 0);
            }
        __syncthreads();   // drains this wave's prefetch (vmcnt) + reads (lgkm)
        cur = nb;
    }

    const int qe = lane >> 4;
    const int cl = lane & 15;
#pragma unroll
    for (int i = 0; i < 4; ++i) {
#pragma unroll
        for (int r = 0; r < 4; ++r) {
            int slot = m0 + wm * 64 + i * 16 + qe * 4 + r;
            if (slot < n) {
                float wgt = tok_w[e * TTOK + slot];
                size_t rowoff = (size_t)(rowbase + slot) * IDIM + i0 + wn * 64 + cl;
#pragma unroll
                for (int j = 0; j < 4; ++j) {
                    float g = accg[i][j][r];
                    float u = accu[i][j][r];
                    float h = (g / (1.f + __expf(-g))) * u * wgt;
                    hbuf[rowoff + j * 16] = f2bf(h);
                }
            }
        }
    }
}

// Down-proj MFMA GEMM, same BK=32 double-buffered pipeline. Writes disjoint
// f32 partial rows (combine weight already folded into h) -- no atomics.
__launch_bounds__(256)
__global__ void down_mfma(const unsigned short* __restrict__ hbuf,
                          const unsigned short* __restrict__ dw,
                          const int* __restrict__ cnt, const int* __restrict__ offs,
                          float* __restrict__ pbuf) {
    const int e = blockIdx.z;
    const int n = cnt[e];
    const int m0 = blockIdx.y * 128;
    if (m0 >= n) return;
    const int h0 = blockIdx.x * 128;
    const int rowbase = offs[e];

    __shared__ __align__(16) unsigned short sA[2][128 * 32];
    __shared__ __align__(16) unsigned short sB[2][128 * 32];

    const int tid = threadIdx.x;
    const int lane = tid & 63;
    const int wave = tid >> 6;
    const int wm = wave >> 1;
    const int wn = wave & 1;

    const unsigned short* Abase = hbuf + (size_t)(rowbase + m0) * IDIM;
    const unsigned short* Bbase = dw + (size_t)e * HDIM * IDIM + (size_t)h0 * IDIM;

    floatx4 acc[4][4];
#pragma unroll
    for (int i = 0; i < 4; ++i)
#pragma unroll
        for (int j = 0; j < 4; ++j) acc[i][j] = (floatx4){0.f, 0.f, 0.f, 0.f};

    const int srow = lane >> 2;
    const int scol = (lane & 3) * 8;

    auto stage = [&](int buf, int k0) {
#pragma unroll
        for (int q = 0; q < 2; ++q) {
            const int ch = q * 4 + wave;
            const int r = ch * 16 + srow;
            const size_t go = (size_t)r * IDIM + k0 + scol;
            const int lo = ch * 512 + lane * 8;
            __builtin_amdgcn_global_load_lds(GLBP(Abase + go), LDSP(&sA[buf][lo]), 16, 0, 0);
            __builtin_amdgcn_global_load_lds(GLBP(Bbase + go), LDSP(&sB[buf][lo]), 16, 0, 0);
        }
    };

    stage(0, 0);
    __syncthreads();

    const int ko = (lane >> 4) * 8;
    const int mrow = wm * 64 + (lane & 15);
    const int nrow = wn * 64 + (lane & 15);

    int cur = 0;
    for (int k0 = 0; k0 < IDIM; k0 += 32) {
        const int nb = cur ^ 1;
        if (k0 + 32 < IDIM) stage(nb, k0 + 32);

        short8 af[4], bf[4];
#pragma unroll
        for (int i = 0; i < 4; ++i)
            af[i] = *(const short8*)&sA[cur][(mrow + i * 16) * 32 + ko];
#pragma unroll
        for (int j = 0; j < 4; ++j)
            bf[j] = *(const short8*)&sB[cur][(nrow + j * 16) * 32 + ko];
#pragma unroll
        for (int i = 0; i < 4; ++i)
#pragma unroll
            for (int j = 0; j < 4; ++j)
                acc[i][j] = __builtin_amdgcn_mfma_f32_16x16x32_bf16(af[i], bf[j], acc[i][j], 0, 0, 0);
        __syncthreads();
        cur = nb;
    }

    const int qe = lane >> 4;
    const int cl = lane & 15;
#pragma unroll
    for (int i = 0; i < 4; ++i) {
#pragma unroll
        for (int r = 0; r < 4; ++r) {
            int slot = m0 + wm * 64 + i * 16 + qe * 4 + r;
            if (slot < n) {
                float* orow = pbuf + (size_t)(rowbase + slot) * HDIM + h0 + wn * 64 + cl;
#pragma unroll
                for (int j = 0; j < 4; ++j) orow[j * 16] = acc[i][j][r];
            }
        }
    }
}

// Final combine: out[t] = sum of the token's 4 expert partial rows.
__global__ void reduce_out(const float* __restrict__ pbuf, const int* __restrict__ offs,
                           const int* __restrict__ tk_ep, float* __restrict__ out) {
    const int t = blockIdx.x;
    const int tid = threadIdx.x;  // 256 threads x 8 f32 = 2048
    float4 a0 = {0.f, 0.f, 0.f, 0.f}, a1 = {0.f, 0.f, 0.f, 0.f};
#pragma unroll
    for (int k = 0; k < TOPK; ++k) {
        int v = tk_ep[t * TOPK + k];
        int e = v >> 16, pos = v & 0xffff;
        const float4* src = (const float4*)(pbuf + (size_t)(offs[e] + pos) * HDIM + tid * 8);
        float4 b0 = src[0], b1 = src[1];
        a0.x += b0.x; a0.y += b0.y; a0.z += b0.z; a0.w += b0.w;
        a1.x += b1.x; a1.y += b1.y; a1.z += b1.z; a1.w += b1.w;
    }
    float4* dst = (float4*)(out + (size_t)t * HDIM + tid * 8);
    dst[0] = a0; dst[1] = a1;
}

extern "C" void kernel_launch(void* const* d_in, const int* in_sizes, int n_in,
                              void* d_out, int out_size, void* d_ws, size_t ws_size,
                              hipStream_t stream) {
    const float* x      = (const float*)d_in[0];
    const float* logits = (const float*)d_in[1];
    const float* gate_w = (const float*)d_in[2];
    const float* up_w   = (const float*)d_in[3];
    const float* down_w = (const float*)d_in[4];
    float* out = (float*)d_out;

    char* ws = (char*)d_ws;
    // metadata
    int*   cnt    = (int*)(ws);
    int*   offs   = (int*)(ws + 64);
    int*   tok_id = (int*)(ws + 1024);
    float* tok_w  = (float*)(ws + 1024 + TTOK * NEXP * 4);
    int*   tk_ep  = (int*)(ws + 1024 + 2 * TTOK * NEXP * 4);  // 32 KB, ends < 1 MB
    // bf16 weights at 1 MB (gate 1..89 MB, up 89..177 MB, down 177..265 MB)
    unsigned short* gate_bf = (unsigned short*)(ws + (1u << 20));
    unsigned short* up_bf   = gate_bf + GUP;
    unsigned short* down_bf = up_bf + GUP;
    // f32 down partials overlay the gate/up bf16 region (dead after gateup):
    // <=10224 rows * 2048 * 4B = 80 MB, fits in gate_bf's 88 MB footprint.
    float* pbuf = (float*)(ws + (1u << 20));
    // gathered x (<=10224 x 2048 bf16) at 280 MB
    unsigned short* xg   = (unsigned short*)(ws + (size_t)280 * (1u << 20));
    // h buffer (<=10224 x 1408 bf16) at 321 MB
    unsigned short* hbuf = (unsigned short*)(ws + (size_t)321 * (1u << 20));

    zero_i32<<<1, 32, 0, stream>>>(cnt, NEXP);
    cast_weights<<<4096, 256, 0, stream>>>(gate_w, up_w, down_w, gate_bf, up_bf, down_bf);
    router_kernel<<<TTOK / 256, 256, 0, stream>>>(logits, cnt, tok_id, tok_w, tk_ep);
    scan_kernel<<<1, 1, 0, stream>>>(cnt, offs);
    {
        dim3 g(TTOK, NEXP);
        gather_x<<<g, 256, 0, stream>>>(x, cnt, offs, tok_id, xg);
    }
    {
        dim3 g(IDIM / 128, TTOK / 128, NEXP);
        gateup_mfma<<<g, 256, 0, stream>>>(xg, gate_bf, up_bf, cnt, offs, tok_w, hbuf);
    }
    {
        dim3 g(HDIM / 128, TTOK / 128, NEXP);
        down_mfma<<<g, 256, 0, stream>>>(hbuf, down_bf, cnt, offs, pbuf);
    }
    reduce_out<<<TTOK, 256, 0, stream>>>(pbuf, offs, tk_ep, out);
}